// Round 6
// baseline (606.167 us; speedup 1.0000x reference)
//
#include <hip/hip_runtime.h>
#include <hip/hip_bf16.h>

// ---------------------------------------------------------------------------
// MoE dense all-expert forward, MI355X / gfx950.  B=16384, D=H=O=256, E=32.
// Round 6 = round 5 with the spill fixed: __launch_bounds__(512, 1).
//   (hipcc treats the 2nd arg as min blocks/CU, CUDA-style: (512,2) capped
//    VGPRs at 128 and spilled 872 MB to scratch — round 5's regression.)
//  - 128-row x 16-expert blocks (weight traffic 2 GB -> 1 GB from L2)
//  - lgkmcnt-only barriers (prefetches survive barriers; no vmcnt(0) drain)
//  - distance-2 ping-pong register prefetch of weight chunks
//  - eg=0 blocks write out, eg=1 write ws partial; combine kernel adds
// ---------------------------------------------------------------------------

typedef __attribute__((ext_vector_type(8))) short bf16x8;   // 8 bf16 = 4 VGPRs
typedef __attribute__((ext_vector_type(4))) float f32x4;

__device__ __forceinline__ unsigned short f2bf(float f) {
    unsigned u = __builtin_bit_cast(unsigned, f);
    u += 0x7FFFu + ((u >> 16) & 1u);        // round-to-nearest-even
    return (unsigned short)(u >> 16);
}
__device__ __forceinline__ unsigned pack_bf16x2(float a, float b) {
    return (unsigned)f2bf(a) | ((unsigned)f2bf(b) << 16);
}

// barrier that waits only LDS (lgkmcnt), leaving global prefetches in flight
__device__ __forceinline__ void lds_barrier() {
    asm volatile("s_waitcnt lgkmcnt(0)\n\ts_barrier" ::: "memory");
}

// 16B-chunk XOR swizzle for [rows][256 elem] bf16 tiles (index in ushorts)
#define LX(r, ch) (((r) << 8) + ((((ch) ^ ((r) & 7))) << 3))

// ------------------- W f32 -> bf16 convert + tile reorder ------------------
// chunk c = (e*8 + slot)*8 + kb ; slot 0-3 = W1 rows slot*64.., 4-7 = W2.
// chunk = 2048 bf16 = 4 KB; element (t,lane,j): row = slot64 + t*16 + (lane&15),
// k = kb*32 + (lane>>4)*8 + j  — the mfma_16x16x32 A-frag order.
__global__ __launch_bounds__(256) void cvt_w(const float* __restrict__ W1,
                                             const float* __restrict__ W2,
                                             unsigned short* __restrict__ Wr) {
    int T = blockIdx.x * 256 + threadIdx.x;          // 524288 threads
    int lane = T & 63, t = (T >> 6) & 3, kb = (T >> 8) & 7;
    int g = (T >> 11) & 7, e = T >> 14;
    int l15 = lane & 15, quad = lane >> 4;
    int row = (g & 3) * 64 + t * 16 + l15;
    const float* src = ((g < 4) ? W1 : W2) +
                       ((long)e * 256 + row) * 256 + kb * 32 + quad * 8;
    float4 v0 = ((const float4*)src)[0], v1 = ((const float4*)src)[1];
    uint4 o;
    o.x = pack_bf16x2(v0.x, v0.y); o.y = pack_bf16x2(v0.z, v0.w);
    o.z = pack_bf16x2(v1.x, v1.y); o.w = pack_bf16x2(v1.z, v1.w);
    ((uint4*)Wr)[T] = o;
}

// ------------------------------ fused MoE ----------------------------------
// 256 blocks x 512 thr. Block = (row-group rg of 128 rows) x (expert half eg).
// crew0 (waves 0-3): h(e)^T = W1[e].x^T ; crew1 (waves 4-7): acc += W2[e-1].h^T
__global__ __launch_bounds__(512, 1) void moe_kernel(
    const float* __restrict__ x,
    const unsigned short* __restrict__ Wr,
    const float* __restrict__ bias1,
    const float* __restrict__ b2,
    const float* __restrict__ Wg,
    const float* __restrict__ bg,
    float* __restrict__ out,
    float* __restrict__ part1)
{
    __shared__ __align__(16) unsigned short x_s[128 * 256];  // 64 KB
    __shared__ __align__(16) unsigned short h_s[128 * 256];  // 64 KB
    __shared__ float gws[128 * 17];                          // 8.5 KB

    const int tid  = threadIdx.x;
    const int wv   = tid >> 6, lane = tid & 63;
    const int quad = lane >> 4, l15 = lane & 15;
    const int crew = wv >> 2, g = wv & 3;       // crew0 = GEMM1, crew1 = GEMM2
    const int eg   = blockIdx.x & 1;            // expert half (0..15 / 16..31)
    const int rg   = blockIdx.x >> 1;
    const int row0 = rg * 128;
    const int ebase = eg * 16;

    // ---- stage x tile: f32 global -> bf16 LDS (swizzled) ----
#pragma unroll
    for (int c = 0; c < 8; ++c) {
        int chunk = tid + c * 512;              // 4096 chunks of 8 elems
        int r = chunk >> 5, ch = chunk & 31;
        const float4* s = (const float4*)(x + (long)(row0 + r) * 256 + ch * 8);
        float4 v0 = s[0], v1 = s[1];
        uint4 o;
        o.x = pack_bf16x2(v0.x, v0.y); o.y = pack_bf16x2(v0.z, v0.w);
        o.z = pack_bf16x2(v1.x, v1.y); o.w = pack_bf16x2(v1.z, v1.w);
        *(uint4*)(&x_s[LX(r, ch)]) = o;
    }

    // ---- inline gating: 16 rows per wave, all f32 (matches reference) ----
    {
        const int e32 = lane & 31, half = lane >> 5;
        const float4* wg4 = (const float4*)(Wg + e32 * 256 + half * 128);
        float bgv = bg[e32];
        for (int i = 0; i < 16; ++i) {
            int lr = wv * 16 + i;
            const float4* xr4 = (const float4*)(x + (long)(row0 + lr) * 256 + half * 128);
            float acc = 0.f;
#pragma unroll
            for (int tt = 0; tt < 32; ++tt) {
                float4 w = wg4[tt], xv = xr4[tt];
                acc = fmaf(w.x, xv.x, acc); acc = fmaf(w.y, xv.y, acc);
                acc = fmaf(w.z, xv.z, acc); acc = fmaf(w.w, xv.w, acc);
            }
            acc += __shfl_xor(acc, 32);
            float score = (acc + bgv) / 2.71828182845904523f;   // TEMP = e

            float m = score;
#pragma unroll
            for (int d = 16; d >= 1; d >>= 1) m = fmaxf(m, __shfl_xor(m, d));
            float p = expf(score - m);
            float ps = p;
#pragma unroll
            for (int d = 16; d >= 1; d >>= 1) ps += __shfl_xor(ps, d);
            float prob = p / ps;

            int rank = 0;
#pragma unroll
            for (int j = 0; j < 32; ++j) {
                float pj = __shfl(prob, j);
                rank += (pj > prob || (pj == prob && j < e32)) ? 1 : 0;
            }
            float kept = (rank < 22) ? prob : 0.f;
            float wsum = kept;
#pragma unroll
            for (int d = 16; d >= 1; d >>= 1) wsum += __shfl_xor(wsum, d);
            float weight = kept / (wsum + 1e-8f);

            if (half == 0 && (e32 >> 4) == eg)
                gws[lr * 17 + (e32 & 15)] = weight;
        }
    }

    lds_barrier();   // x_s + gws ready

    // ---- crew1: out^T accumulators, init = sum_{local e} gw*b2 ----
    f32x4 oacc[4][8];                           // [ot][rt]
#pragma unroll
    for (int ot = 0; ot < 4; ++ot)
#pragma unroll
        for (int rt = 0; rt < 8; ++rt) {
            f32x4 z = {0.f, 0.f, 0.f, 0.f};
            oacc[ot][rt] = z;
        }
    if (crew == 1) {
        for (int ee = 0; ee < 16; ++ee) {
            float gv[8];
#pragma unroll
            for (int rt = 0; rt < 8; ++rt) gv[rt] = gws[(rt * 16 + l15) * 17 + ee];
#pragma unroll
            for (int ot = 0; ot < 4; ++ot) {
                float4 bb = *(const float4*)(b2 + (ebase + ee) * 256 + g * 64 + ot * 16 + quad * 4);
#pragma unroll
                for (int rt = 0; rt < 8; ++rt) {
                    oacc[ot][rt][0] = fmaf(gv[rt], bb.x, oacc[ot][rt][0]);
                    oacc[ot][rt][1] = fmaf(gv[rt], bb.y, oacc[ot][rt][1]);
                    oacc[ot][rt][2] = fmaf(gv[rt], bb.z, oacc[ot][rt][2]);
                    oacc[ot][rt][3] = fmaf(gv[rt], bb.w, oacc[ot][rt][3]);
                }
            }
        }
    }

    // ---- weight stream: per-wave base; expert stride 131072, kb stride 2048 ----
    const unsigned short* wbase = Wr + ((long)ebase * 8 + wv) * 16384;

    // preload chunks (local expert 0, kb 0 and 1) — distance-2 ping-pong
    bf16x8 q0[4], q1[4];
#pragma unroll
    for (int t = 0; t < 4; ++t) q0[t] = *(const bf16x8*)(wbase + t * 512 + lane * 8);
#pragma unroll
    for (int t = 0; t < 4; ++t) q1[t] = *(const bf16x8*)(wbase + 2048 + t * 512 + lane * 8);

    // ---- expert pipeline: crew0 computes e, crew1 computes e-1 ----
#pragma unroll 1
    for (int e = 0; e <= 16; ++e) {
        f32x4 hacc[4][8];                       // crew0 transient [ht][rt]
        if (crew == 0) {
            if (e < 16) {
#pragma unroll
                for (int ht = 0; ht < 4; ++ht)
#pragma unroll
                    for (int rt = 0; rt < 8; ++rt) {
                        f32x4 z = {0.f, 0.f, 0.f, 0.f};
                        hacc[ht][rt] = z;
                    }
                const unsigned short* wcur = wbase + (long)e * 131072;
#pragma unroll
                for (int kb = 0; kb < 8; ++kb) {
                    bf16x8 bx[8];
#pragma unroll
                    for (int rt = 0; rt < 8; ++rt)
                        bx[rt] = *(const bf16x8*)(&x_s[LX(rt * 16 + l15, kb * 4 + quad)]);
#pragma unroll
                    for (int ht = 0; ht < 4; ++ht)
#pragma unroll
                        for (int rt = 0; rt < 8; ++rt)
                            hacc[ht][rt] = __builtin_amdgcn_mfma_f32_16x16x32_bf16(
                                q0[ht], bx[rt], hacc[ht][rt], 0, 0, 0);
                    // rotate + prefetch distance 2
#pragma unroll
                    for (int t = 0; t < 4; ++t) q0[t] = q1[t];
                    const unsigned short* pf = (kb < 6)
                        ? (wcur + (kb + 2) * 2048)
                        : (wcur + 131072 + (kb - 6) * 2048);
#pragma unroll
                    for (int t = 0; t < 4; ++t)
                        q1[t] = *(const bf16x8*)(pf + t * 512 + lane * 8);
                }
            }
        } else {
            if (e >= 1) {
                const unsigned short* wcur = wbase + (long)(e - 1) * 131072;
#pragma unroll
                for (int kb = 0; kb < 8; ++kb) {
                    bf16x8 bx[8];
#pragma unroll
                    for (int rt = 0; rt < 8; ++rt)
                        bx[rt] = *(const bf16x8*)(&h_s[LX(rt * 16 + l15, kb * 4 + quad)]);
#pragma unroll
                    for (int ot = 0; ot < 4; ++ot)
#pragma unroll
                        for (int rt = 0; rt < 8; ++rt)
                            oacc[ot][rt] = __builtin_amdgcn_mfma_f32_16x16x32_bf16(
                                q0[ot], bx[rt], oacc[ot][rt], 0, 0, 0);
#pragma unroll
                    for (int t = 0; t < 4; ++t) q0[t] = q1[t];
                    const unsigned short* pf = (kb < 6)
                        ? (wcur + (kb + 2) * 2048)
                        : (wcur + 131072 + (kb - 6) * 2048);
#pragma unroll
                    for (int t = 0; t < 4; ++t)
                        q1[t] = *(const bf16x8*)(pf + t * 512 + lane * 8);
                }
            }
        }

        lds_barrier();   // crew1 done reading h_s(e-1); crew0 hacc(e) ready

        if (crew == 0 && e < 16) {
            // epilogue: +b1, relu, * gate weight, packed b64 -> h_s
            float4 bv[4]; float gw[8];
#pragma unroll
            for (int ht = 0; ht < 4; ++ht)
                bv[ht] = *(const float4*)(bias1 + (ebase + e) * 256 + g * 64 + ht * 16 + quad * 4);
#pragma unroll
            for (int rt = 0; rt < 8; ++rt)
                gw[rt] = gws[(rt * 16 + l15) * 17 + e];
#pragma unroll
            for (int ht = 0; ht < 4; ++ht) {
                int hb = g * 64 + ht * 16 + quad * 4;   // 4 consecutive h-cols
                int ch = hb >> 3, off = hb & 7;
#pragma unroll
                for (int rt = 0; rt < 8; ++rt) {
                    int r = rt * 16 + l15;
                    float v0 = fmaxf(hacc[ht][rt][0] + bv[ht].x, 0.f) * gw[rt];
                    float v1 = fmaxf(hacc[ht][rt][1] + bv[ht].y, 0.f) * gw[rt];
                    float v2 = fmaxf(hacc[ht][rt][2] + bv[ht].z, 0.f) * gw[rt];
                    float v3 = fmaxf(hacc[ht][rt][3] + bv[ht].w, 0.f) * gw[rt];
                    uint2 p;
                    p.x = pack_bf16x2(v0, v1);
                    p.y = pack_bf16x2(v2, v3);
                    *(uint2*)(&h_s[(r << 8) + ((ch ^ (r & 7)) << 3) + off]) = p;
                }
            }
        }

        lds_barrier();   // h_s(e) final, visible to crew1 next phase
    }

    // ---- final store: out^T frags -> out (eg=0) or partial (eg=1) ----
    if (crew == 1) {
        float* po = ((eg == 0) ? out : part1) + (long)row0 * 256;
#pragma unroll
        for (int ot = 0; ot < 4; ++ot)
#pragma unroll
            for (int rt = 0; rt < 8; ++rt)
                *(f32x4*)(po + (long)(rt * 16 + l15) * 256 +
                          g * 64 + ot * 16 + quad * 4) = oacc[ot][rt];
    }
}

// ------------------------------ combine ------------------------------------
__global__ __launch_bounds__(256) void combine(const float* __restrict__ p1,
                                               float* __restrict__ out) {
    int i = blockIdx.x * 256 + threadIdx.x;     // 1M float4
    float4 a = ((const float4*)out)[i];
    float4 b = ((const float4*)p1)[i];
    a.x += b.x; a.y += b.y; a.z += b.z; a.w += b.w;
    ((float4*)out)[i] = a;
}

// ------------------------------- launch ------------------------------------
extern "C" void kernel_launch(void* const* d_in, const int* in_sizes, int n_in,
                              void* d_out, int out_size, void* d_ws, size_t ws_size,
                              hipStream_t stream) {
    (void)in_sizes; (void)n_in; (void)out_size; (void)ws_size;
    const float* x  = (const float*)d_in[0];   // [16384,256]
    const float* W1 = (const float*)d_in[1];   // [32,256,256]
    const float* b1 = (const float*)d_in[2];   // [32,256]
    const float* W2 = (const float*)d_in[3];   // [32,256,256]
    const float* b2 = (const float*)d_in[4];   // [32,256]
    const float* Wg = (const float*)d_in[5];   // [32,256]
    const float* bg = (const float*)d_in[6];   // [32]
    float* out = (float*)d_out;                // [16384,256]

    // ws: Wr (32 experts + prefetch-overrun pad) = 8.65 MB at offset 0;
    //     part1 (16 MB) at offset 16 MB. Total 32 MB.
    unsigned short* Wr    = (unsigned short*)d_ws;
    float*          part1 = (float*)((char*)d_ws + (16u << 20));

    cvt_w<<<2048, 256, 0, stream>>>(W1, W2, Wr);
    moe_kernel<<<256, 512, 0, stream>>>(x, Wr, b1, b2, Wg, bg, out, part1);
    combine<<<4096, 256, 0, stream>>>(part1, out);
}

// Round 7
// 319.020 us; speedup vs baseline: 1.9001x; 1.9001x over previous
//
#include <hip/hip_runtime.h>
#include <hip/hip_bf16.h>

// ---------------------------------------------------------------------------
// MoE dense all-expert forward, MI355X / gfx950.  B=16384, D=H=O=256, E=32.
// Round 7: 256-thread blocks (4 waves = 1 wave/SIMD -> 512-reg budget, no
// spill by construction), sequential GEMM1/GEMM2 phases (no crew split).
//  - block = 128 batch rows x 16 experts (eg half); 256 blocks = 1/CU
//  - per wave: 64 H/O cols x 128 rows (hacc/oacc 4x8 f32x4 = 128 regs each)
//  - weights reordered into per-(expert,phase,wave,kb) 4 KB chunks; linear
//    stream, distance-2 ping-pong register prefetch; lgkm-only barriers
//  - eg = blockIdx&1 => each XCD touches only one 4 MB weight half (L2 fit)
// ---------------------------------------------------------------------------

typedef __attribute__((ext_vector_type(8))) short bf16x8;   // 8 bf16 = 4 VGPRs
typedef __attribute__((ext_vector_type(4))) float f32x4;

__device__ __forceinline__ unsigned short f2bf(float f) {
    unsigned u = __builtin_bit_cast(unsigned, f);
    u += 0x7FFFu + ((u >> 16) & 1u);        // round-to-nearest-even
    return (unsigned short)(u >> 16);
}
__device__ __forceinline__ unsigned pack_bf16x2(float a, float b) {
    return (unsigned)f2bf(a) | ((unsigned)f2bf(b) << 16);
}

// barrier that waits only LDS (lgkmcnt), leaving global prefetches in flight
__device__ __forceinline__ void lds_barrier() {
    asm volatile("s_waitcnt lgkmcnt(0)\n\ts_barrier" ::: "memory");
}

// 16B-chunk XOR swizzle for [rows][256 elem] bf16 tiles (index in ushorts)
#define LX(r, ch) (((r) << 8) + ((((ch) ^ ((r) & 7))) << 3))

// ------------------- W f32 -> bf16 convert + tile reorder ------------------
// Global chunk c = ((e*2 + ph)*4 + wv)*8 + kb, 2048 bf16 = 4 KB each.
// Element (ht, lane, j): W row = wv*64 + ht*16 + (lane&15),
//                        k     = kb*32 + (lane>>4)*8 + j   (A-frag order).
__global__ __launch_bounds__(256) void cvt_w(const float* __restrict__ W1,
                                             const float* __restrict__ W2,
                                             unsigned short* __restrict__ Wr) {
    int T = blockIdx.x * 256 + threadIdx.x;          // 524288 threads
    int c = T >> 8, tsub = T & 255;
    int lane = tsub & 63, ht = tsub >> 6;
    int kb = c & 7, wv = (c >> 3) & 3, ph = (c >> 5) & 1, e = c >> 6;
    int row = wv * 64 + ht * 16 + (lane & 15);
    int k = kb * 32 + (lane >> 4) * 8;
    const float* src = ((ph == 0) ? W1 : W2) + ((long)e * 256 + row) * 256 + k;
    float4 v0 = ((const float4*)src)[0], v1 = ((const float4*)src)[1];
    uint4 o;
    o.x = pack_bf16x2(v0.x, v0.y); o.y = pack_bf16x2(v0.z, v0.w);
    o.z = pack_bf16x2(v1.x, v1.y); o.w = pack_bf16x2(v1.z, v1.w);
    *(uint4*)(Wr + (long)c * 2048 + ht * 512 + lane * 8) = o;
}

// ------------------------------ fused MoE ----------------------------------
// 256 blocks x 256 thr (4 waves, 1/SIMD). Block = (rg of 128 rows) x (eg).
__global__ __launch_bounds__(256) void moe_kernel(
    const float* __restrict__ x,
    const unsigned short* __restrict__ Wr,
    const float* __restrict__ bias1,
    const float* __restrict__ b2,
    const float* __restrict__ Wg,
    const float* __restrict__ bg,
    float* __restrict__ out,
    float* __restrict__ part1)
{
    __shared__ __align__(16) unsigned short x_s[128 * 256];  // 64 KB
    __shared__ __align__(16) unsigned short h_s[128 * 256];  // 64 KB
    __shared__ float gws[128 * 17];                          // 8.5 KB

    const int tid  = threadIdx.x;
    const int wv   = tid >> 6, lane = tid & 63;
    const int quad = lane >> 4, l15 = lane & 15;
    const int eg   = blockIdx.x & 1;            // expert half (0..15 / 16..31)
    const int rg   = blockIdx.x >> 1;
    const int row0 = rg * 128;
    const int ebase = eg * 16;

    // ---- stage x tile: f32 global -> bf16 LDS (swizzled) ----
#pragma unroll
    for (int c = 0; c < 16; ++c) {
        int chunk = tid + c * 256;              // 4096 chunks of 8 elems
        int r = chunk >> 5, ch = chunk & 31;
        const float4* s = (const float4*)(x + (long)(row0 + r) * 256 + ch * 8);
        float4 v0 = s[0], v1 = s[1];
        uint4 o;
        o.x = pack_bf16x2(v0.x, v0.y); o.y = pack_bf16x2(v0.z, v0.w);
        o.z = pack_bf16x2(v1.x, v1.y); o.w = pack_bf16x2(v1.z, v1.w);
        *(uint4*)(&x_s[LX(r, ch)]) = o;
    }

    // ---- inline gating: 32 rows per wave, all f32 (matches reference) ----
    {
        const int e32 = lane & 31, half = lane >> 5;
        const float4* wg4 = (const float4*)(Wg + e32 * 256 + half * 128);
        float bgv = bg[e32];
        for (int i = 0; i < 32; ++i) {
            int lr = wv * 32 + i;
            const float4* xr4 = (const float4*)(x + (long)(row0 + lr) * 256 + half * 128);
            float acc = 0.f;
#pragma unroll
            for (int tt = 0; tt < 32; ++tt) {
                float4 w = wg4[tt], xv = xr4[tt];
                acc = fmaf(w.x, xv.x, acc); acc = fmaf(w.y, xv.y, acc);
                acc = fmaf(w.z, xv.z, acc); acc = fmaf(w.w, xv.w, acc);
            }
            acc += __shfl_xor(acc, 32);
            float score = (acc + bgv) / 2.71828182845904523f;   // TEMP = e

            float m = score;
#pragma unroll
            for (int d = 16; d >= 1; d >>= 1) m = fmaxf(m, __shfl_xor(m, d));
            float p = expf(score - m);
            float ps = p;
#pragma unroll
            for (int d = 16; d >= 1; d >>= 1) ps += __shfl_xor(ps, d);
            float prob = p / ps;

            int rank = 0;
#pragma unroll
            for (int j = 0; j < 32; ++j) {
                float pj = __shfl(prob, j);
                rank += (pj > prob || (pj == prob && j < e32)) ? 1 : 0;
            }
            float kept = (rank < 22) ? prob : 0.f;
            float wsum = kept;
#pragma unroll
            for (int d = 16; d >= 1; d >>= 1) wsum += __shfl_xor(wsum, d);
            float weight = kept / (wsum + 1e-8f);

            if (half == 0 && (e32 >> 4) == eg)
                gws[lr * 17 + (e32 & 15)] = weight;
        }
    }

    lds_barrier();   // x_s + gws ready

    // ---- out^T accumulators (all waves), init = sum_{local e} gw*b2 ----
    f32x4 oacc[4][8];                           // [ot][rt]
#pragma unroll
    for (int ot = 0; ot < 4; ++ot)
#pragma unroll
        for (int rt = 0; rt < 8; ++rt) {
            f32x4 z = {0.f, 0.f, 0.f, 0.f};
            oacc[ot][rt] = z;
        }
    for (int ee = 0; ee < 16; ++ee) {
        float gv[8];
#pragma unroll
        for (int rt = 0; rt < 8; ++rt) gv[rt] = gws[(rt * 16 + l15) * 17 + ee];
#pragma unroll
        for (int ot = 0; ot < 4; ++ot) {
            float4 bb = *(const float4*)(b2 + (ebase + ee) * 256 + wv * 64 + ot * 16 + quad * 4);
#pragma unroll
            for (int rt = 0; rt < 8; ++rt) {
                oacc[ot][rt][0] = fmaf(gv[rt], bb.x, oacc[ot][rt][0]);
                oacc[ot][rt][1] = fmaf(gv[rt], bb.y, oacc[ot][rt][1]);
                oacc[ot][rt][2] = fmaf(gv[rt], bb.z, oacc[ot][rt][2]);
                oacc[ot][rt][3] = fmaf(gv[rt], bb.w, oacc[ot][rt][3]);
            }
        }
    }

    // ---- weight stream: linear groups of 8 chunks; group stride 65536 elems.
    // group G = (ebase + e_local)*2 + ph ; chunk addr = G*65536 + wv*16384 + kb*2048
    const unsigned short* wbase = Wr + (long)(ebase * 2) * 65536 + wv * 16384;

    // distance-2 ping-pong preload (expert 0, ph 0, kb 0 and 1)
    bf16x8 q0[4], q1[4];
#pragma unroll
    for (int t = 0; t < 4; ++t) q0[t] = *(const bf16x8*)(wbase + t * 512 + lane * 8);
#pragma unroll
    for (int t = 0; t < 4; ++t) q1[t] = *(const bf16x8*)(wbase + 2048 + t * 512 + lane * 8);

    // ---- expert loop: GEMM1 -> epilogue -> barrier -> GEMM2 -> barrier ----
#pragma unroll 1
    for (int e = 0; e < 16; ++e) {
        const unsigned short* pcur = wbase + (long)(2 * e) * 65536;   // ph0 group

        // ---- GEMM1: hacc = W1[e] . x^T ----
        f32x4 hacc[4][8];
#pragma unroll
        for (int ht = 0; ht < 4; ++ht)
#pragma unroll
            for (int rt = 0; rt < 8; ++rt) {
                f32x4 z = {0.f, 0.f, 0.f, 0.f};
                hacc[ht][rt] = z;
            }
#pragma unroll
        for (int kb = 0; kb < 8; ++kb) {
            bf16x8 bx[8];
#pragma unroll
            for (int rt = 0; rt < 8; ++rt)
                bx[rt] = *(const bf16x8*)(&x_s[LX(rt * 16 + l15, kb * 4 + quad)]);
#pragma unroll
            for (int ht = 0; ht < 4; ++ht)
#pragma unroll
                for (int rt = 0; rt < 8; ++rt)
                    hacc[ht][rt] = __builtin_amdgcn_mfma_f32_16x16x32_bf16(
                        q0[ht], bx[rt], hacc[ht][rt], 0, 0, 0);
            // rotate + distance-2 prefetch (stream idx kb+2 within 16-chunk window)
#pragma unroll
            for (int t = 0; t < 4; ++t) q0[t] = q1[t];
            const unsigned short* pf = pcur + ((kb + 2) >> 3) * 65536 + ((kb + 2) & 7) * 2048;
#pragma unroll
            for (int t = 0; t < 4; ++t)
                q1[t] = *(const bf16x8*)(pf + t * 512 + lane * 8);
        }

        // ---- epilogue: +b1, relu, * gate weight, packed b64 -> h_s ----
        {
            float4 bv[4]; float gw[8];
#pragma unroll
            for (int ht = 0; ht < 4; ++ht)
                bv[ht] = *(const float4*)(bias1 + (ebase + e) * 256 + wv * 64 + ht * 16 + quad * 4);
#pragma unroll
            for (int rt = 0; rt < 8; ++rt)
                gw[rt] = gws[(rt * 16 + l15) * 17 + e];
#pragma unroll
            for (int ht = 0; ht < 4; ++ht) {
                int hb = wv * 64 + ht * 16 + quad * 4;  // 4 consecutive h-cols
                int ch = hb >> 3, off = hb & 7;
#pragma unroll
                for (int rt = 0; rt < 8; ++rt) {
                    int r = rt * 16 + l15;
                    float v0 = fmaxf(hacc[ht][rt][0] + bv[ht].x, 0.f) * gw[rt];
                    float v1 = fmaxf(hacc[ht][rt][1] + bv[ht].y, 0.f) * gw[rt];
                    float v2 = fmaxf(hacc[ht][rt][2] + bv[ht].z, 0.f) * gw[rt];
                    float v3 = fmaxf(hacc[ht][rt][3] + bv[ht].w, 0.f) * gw[rt];
                    uint2 p;
                    p.x = pack_bf16x2(v0, v1);
                    p.y = pack_bf16x2(v2, v3);
                    *(uint2*)(&h_s[(r << 8) + ((ch ^ (r & 7)) << 3) + off]) = p;
                }
            }
        }

        lds_barrier();   // h_s(e) ready for all waves

        // ---- GEMM2: oacc += W2[e] . h^T ----
        const unsigned short* pcur2 = pcur + 65536;                    // ph1 group
#pragma unroll
        for (int kb = 0; kb < 8; ++kb) {
            bf16x8 bh[8];
#pragma unroll
            for (int rt = 0; rt < 8; ++rt)
                bh[rt] = *(const bf16x8*)(&h_s[LX(rt * 16 + l15, kb * 4 + quad)]);
#pragma unroll
            for (int ot = 0; ot < 4; ++ot)
#pragma unroll
                for (int rt = 0; rt < 8; ++rt)
                    oacc[ot][rt] = __builtin_amdgcn_mfma_f32_16x16x32_bf16(
                        q0[ot], bh[rt], oacc[ot][rt], 0, 0, 0);
#pragma unroll
            for (int t = 0; t < 4; ++t) q0[t] = q1[t];
            const unsigned short* pf = pcur2 + ((kb + 2) >> 3) * 65536 + ((kb + 2) & 7) * 2048;
#pragma unroll
            for (int t = 0; t < 4; ++t)
                q1[t] = *(const bf16x8*)(pf + t * 512 + lane * 8);
        }

        lds_barrier();   // h_s consumed; next expert's epilogue may overwrite
    }

    // ---- final store: out^T frags -> out (eg=0) or partial (eg=1) ----
    {
        float* po = ((eg == 0) ? out : part1) + (long)row0 * 256;
#pragma unroll
        for (int ot = 0; ot < 4; ++ot)
#pragma unroll
            for (int rt = 0; rt < 8; ++rt)
                *(f32x4*)(po + (long)(rt * 16 + l15) * 256 +
                          wv * 64 + ot * 16 + quad * 4) = oacc[ot][rt];
    }
}

// ------------------------------ combine ------------------------------------
__global__ __launch_bounds__(256) void combine(const float* __restrict__ p1,
                                               float* __restrict__ out) {
    int i = blockIdx.x * 256 + threadIdx.x;     // 1M float4
    float4 a = ((const float4*)out)[i];
    float4 b = ((const float4*)p1)[i];
    a.x += b.x; a.y += b.y; a.z += b.z; a.w += b.w;
    ((float4*)out)[i] = a;
}

// ------------------------------- launch ------------------------------------
extern "C" void kernel_launch(void* const* d_in, const int* in_sizes, int n_in,
                              void* d_out, int out_size, void* d_ws, size_t ws_size,
                              hipStream_t stream) {
    (void)in_sizes; (void)n_in; (void)out_size; (void)ws_size;
    const float* x  = (const float*)d_in[0];   // [16384,256]
    const float* W1 = (const float*)d_in[1];   // [32,256,256]
    const float* b1 = (const float*)d_in[2];   // [32,256]
    const float* W2 = (const float*)d_in[3];   // [32,256,256]
    const float* b2 = (const float*)d_in[4];   // [32,256]
    const float* Wg = (const float*)d_in[5];   // [32,256]
    const float* bg = (const float*)d_in[6];   // [32]
    float* out = (float*)d_out;                // [16384,256]

    // ws: Wr 8 MB (+128 KB prefetch-overrun pad) at 0; part1 16 MB at 16 MB.
    unsigned short* Wr    = (unsigned short*)d_ws;
    float*          part1 = (float*)((char*)d_ws + (16u << 20));

    cvt_w<<<2048, 256, 0, stream>>>(W1, W2, Wr);
    moe_kernel<<<256, 256, 0, stream>>>(x, Wr, b1, b2, Wg, bg, out, part1);
    combine<<<4096, 256, 0, stream>>>(part1, out);
}